// Round 6
// baseline (357.308 us; speedup 1.0000x reference)
//
#include <hip/hip_runtime.h>
#include <hip/hip_bf16.h>

// NT-Xent loss. N=4096 pairs, D=1024, 2N=8192 rows.
// loss = 1/T + mean_i log( sum_{j != i} exp(sim_ij - 1/T) ) - mean_i pos_i
// sim = Z Z^T (cosine); fixed max 1/T (cosine bound) -> no online max.
// R2: triangular symmetry (each pair feeds row+col sums).
// R5: 496 off-diag 256^2 cells = 2 clean dispatch rounds; diag band peeled.
// R6: fp8 e4m3 + mfma_scale_f32_32x32x64_f8f6f4 (unit E8M0 scales).
//     Halves LDS traffic, doubles MFMA rate, K=64/instr -> 2 barriers/K-tile.
//     pos pairs stay fp32-exact; diagonal masked exactly; fp8 noise ~1e-3
//     on a 0.18 threshold.

#define NPAIR 4096
#define NROWS 8192
#define DIM   1024
#define NOFF  496                   // strict off-diag 256^2 cells (32*31/2)
#define NKT   16                    // K-tiles of 64
#define INV_T 14.285714285714286f   // 1/0.07
#define SCL1  0x7F                  // E8M0 exponent 127 -> scale 2^0 = 1.0

typedef __attribute__((ext_vector_type(4)))  int   i32x4;
typedef __attribute__((ext_vector_type(8)))  int   i32x8;
typedef __attribute__((ext_vector_type(16))) float f32x16;

#define GLOAD_LDS16(g, l)                                              \
  __builtin_amdgcn_global_load_lds(                                    \
      (const __attribute__((address_space(1))) void*)(g),              \
      (__attribute__((address_space(3))) void*)(l), 16, 0, 0)

#define MFMA_FP8(A, B, C)                                              \
  __builtin_amdgcn_mfma_scale_f32_32x32x64_f8f6f4(                     \
      (A), (B), (C), 0, 0, 0, SCL1, 0, SCL1)

// ---------------------------------------------------------------------------
// Kernel A: per pair-row i: norms + cross dot (fp32); write fp8 e4m3
// normalized rows Z[i], Z[i+NPAIR]; pos[i] = cos/T; zero rowsum (2/block).
// ---------------------------------------------------------------------------
__global__ __launch_bounds__(256) void normalize_kernel(
    const float* __restrict__ l1, const float* __restrict__ l2,
    unsigned char* __restrict__ Z, float* __restrict__ pos,
    float* __restrict__ rowsum) {
  const int i = blockIdx.x;
  const int t = threadIdx.x;           // one float4 per thread
  if (t < 2) rowsum[i * 2 + t] = 0.f;
  const float4 a = ((const float4*)(l1 + (size_t)i * DIM))[t];
  const float4 b = ((const float4*)(l2 + (size_t)i * DIM))[t];
  float s1 = a.x*a.x + a.y*a.y + a.z*a.z + a.w*a.w;
  float s2 = b.x*b.x + b.y*b.y + b.z*b.z + b.w*b.w;
  float d  = a.x*b.x + a.y*b.y + a.z*b.z + a.w*b.w;

  #pragma unroll
  for (int off = 32; off; off >>= 1) {
    s1 += __shfl_down(s1, off);
    s2 += __shfl_down(s2, off);
    d  += __shfl_down(d,  off);
  }
  __shared__ float red[3][4];
  __shared__ float fin[3];
  const int wave = t >> 6, lane = t & 63;
  if (lane == 0) { red[0][wave] = s1; red[1][wave] = s2; red[2][wave] = d; }
  __syncthreads();
  if (t == 0) {
    float S1 = red[0][0] + red[0][1] + red[0][2] + red[0][3];
    float S2 = red[1][0] + red[1][1] + red[1][2] + red[1][3];
    float DD = red[2][0] + red[2][1] + red[2][2] + red[2][3];
    float r1 = rsqrtf(S1), r2 = rsqrtf(S2);
    fin[0] = r1; fin[1] = r2;
    pos[i] = DD * r1 * r2 * INV_T;
  }
  __syncthreads();
  const float r1 = fin[0], r2 = fin[1];
  int pa = __builtin_amdgcn_cvt_pk_fp8_f32(a.x * r1, a.y * r1, 0, false);
  pa     = __builtin_amdgcn_cvt_pk_fp8_f32(a.z * r1, a.w * r1, pa, true);
  int pb = __builtin_amdgcn_cvt_pk_fp8_f32(b.x * r2, b.y * r2, 0, false);
  pb     = __builtin_amdgcn_cvt_pk_fp8_f32(b.z * r2, b.w * r2, pb, true);
  ((int*)(Z + (size_t)i * DIM))[t] = pa;
  ((int*)(Z + (size_t)(i + NPAIR) * DIM))[t] = pb;
}

// ---------------------------------------------------------------------------
// Kernel B1: 496 strict off-diagonal 256x256 cells, fp8 MX GEMM.
// Per wave (8 waves, 2Mx4N): output 128x64 = 4 M-frags x 2 N-frags of 32x32.
// BK=64 (one MFMA per frag per K-tile), 3-buffer LDS (96 KB), 2-deep
// prefetch via global_load_lds, counted vmcnt(4), 1 barrier per K-tile.
// A/B frag layout: row/col = lane&31, k = (lane>>5)*32 + [0..31] contiguous.
// LDS 16B-chunk XOR swizzle: phys = logical ^ (r&3) ^ ((r>>2)&3).
// ---------------------------------------------------------------------------
__global__ __launch_bounds__(512) void ntxent_gemm_offdiag(
    const unsigned char* __restrict__ Z, float* __restrict__ rowsum) {
  __shared__ unsigned char lds[3 * 32768];   // buf: A[256][64]@0, B[256][64]@16384

  const int t    = threadIdx.x;
  const int wid  = t >> 6;
  const int lane = t & 63;
  const int l31  = lane & 31;
  const int hi   = lane >> 5;
  const int wm   = wid >> 2;        // 0..1: 128-row half
  const int wn   = wid & 3;         // 0..3: 64-col quarter

  // T1: bijective XCD swizzle (496 = 8*62) + strict-upper decode (bi < bj).
  const int idx = (blockIdx.x & 7) * 62 + (blockIdx.x >> 3);
  int bj = (int)((1.0f + sqrtf(1.0f + 8.0f * (float)idx)) * 0.5f);
  while (bj * (bj - 1) / 2 > idx) --bj;
  while ((bj + 1) * bj / 2 <= idx) ++bj;
  const int bi = idx - bj * (bj - 1) / 2;
  const int brow = bi * 256, bcol = bj * 256;

  // Stage one 256x64 fp8 op-tile (16 KB = 1024 16B-chunks; 2 gloads/wave).
  auto stage = [&](int kt, int buf, int rowbase, int opoff) {
    #pragma unroll
    for (int i = 0; i < 2; ++i) {
      const int cb = wid * 128 + i * 64;     // wave-uniform chunk base
      const int c  = cb + lane;
      const int r  = c >> 2;
      const int lc = (c & 3) ^ (r & 3) ^ ((r >> 2) & 3);
      GLOAD_LDS16(Z + (size_t)(rowbase + r) * DIM + kt * 64 + lc * 16,
                  lds + buf * 32768 + opoff + cb * 16);
    }
  };
  // Read one lane's 32-byte fragment (row = frag row, k = hi*32 + [0..31]).
  auto frag = [&](int buf, int opoff, int row) -> i32x8 {
    const unsigned char* base = lds + buf * 32768 + opoff + row * 64;
    const int swz = (row & 3) ^ ((row >> 2) & 3);
    const i32x4 lo = *(const i32x4*)(base + (((2 * hi)     ^ swz) << 4));
    const i32x4 hp = *(const i32x4*)(base + (((2 * hi + 1) ^ swz) << 4));
    i32x8 r8;
    r8[0] = lo[0]; r8[1] = lo[1]; r8[2] = lo[2]; r8[3] = lo[3];
    r8[4] = hp[0]; r8[5] = hp[1]; r8[6] = hp[2]; r8[7] = hp[3];
    return r8;
  };

  f32x16 acc[4][2];
  #pragma unroll
  for (int mi = 0; mi < 4; ++mi)
    #pragma unroll
    for (int ni = 0; ni < 2; ++ni)
      #pragma unroll
      for (int g = 0; g < 16; ++g) acc[mi][ni][g] = 0.f;

  // Prologue: stage tiles 0,1; drain tile 0 (vmcnt 4 = allow tile1's 4).
  stage(0, 0, brow, 0); stage(0, 0, bcol, 16384);
  stage(1, 1, brow, 0); stage(1, 1, bcol, 16384);
  asm volatile("s_waitcnt vmcnt(4)" ::: "memory");
  __builtin_amdgcn_s_barrier();

  int bcur = 0, bnext = 1, bfree = 2;
  for (int kt = 0; kt < NKT; ++kt) {
    i32x8 A0 = frag(bcur, 0, wm * 128 + 0  + l31);
    i32x8 A1 = frag(bcur, 0, wm * 128 + 32 + l31);
    i32x8 A2 = frag(bcur, 0, wm * 128 + 64 + l31);
    i32x8 A3 = frag(bcur, 0, wm * 128 + 96 + l31);
    i32x8 B0 = frag(bcur, 16384, wn * 64 + 0  + l31);
    i32x8 B1 = frag(bcur, 16384, wn * 64 + 32 + l31);
    if (kt + 2 < NKT) {                      // prefetch 2 ahead
      stage(kt + 2, bfree, brow, 0);
      stage(kt + 2, bfree, bcol, 16384);
    }
    asm volatile("s_waitcnt lgkmcnt(0)" ::: "memory");
    __builtin_amdgcn_sched_barrier(0);
    __builtin_amdgcn_s_setprio(1);
    acc[0][0] = MFMA_FP8(A0, B0, acc[0][0]);
    acc[0][1] = MFMA_FP8(A0, B1, acc[0][1]);
    acc[1][0] = MFMA_FP8(A1, B0, acc[1][0]);
    acc[1][1] = MFMA_FP8(A1, B1, acc[1][1]);
    acc[2][0] = MFMA_FP8(A2, B0, acc[2][0]);
    acc[2][1] = MFMA_FP8(A2, B1, acc[2][1]);
    acc[3][0] = MFMA_FP8(A3, B0, acc[3][0]);
    acc[3][1] = MFMA_FP8(A3, B1, acc[3][1]);
    __builtin_amdgcn_s_setprio(0);
    if (kt + 2 < NKT) {
      asm volatile("s_waitcnt vmcnt(4)" ::: "memory");   // tile kt+1 ready
    } else if (kt + 1 < NKT) {
      asm volatile("s_waitcnt vmcnt(0)" ::: "memory");   // last tile
    }
    __builtin_amdgcn_s_barrier();
    const int tmp = bcur; bcur = bnext; bnext = bfree; bfree = tmp;
  }

  // Epilogue. 32x32 C/D layout: col = lane&31, row = (g&3)+8*(g>>2)+4*hi.
  // Strict off-diag cell: every element is a valid pair, no mask.
  #pragma unroll
  for (int mi = 0; mi < 4; ++mi)
    #pragma unroll
    for (int ni = 0; ni < 2; ++ni)
      #pragma unroll
      for (int g = 0; g < 16; ++g)
        acc[mi][ni][g] = __expf((acc[mi][ni][g] - 1.0f) * INV_T);
  // Row sums: reduce across the 32 cols (lanes within each hi half).
  #pragma unroll
  for (int mi = 0; mi < 4; ++mi)
    #pragma unroll
    for (int g = 0; g < 16; ++g) {
      float s = acc[mi][0][g] + acc[mi][1][g];
      s += __shfl_xor(s, 1);
      s += __shfl_xor(s, 2);
      s += __shfl_xor(s, 4);
      s += __shfl_xor(s, 8);
      s += __shfl_xor(s, 16);
      if (l31 == 0)
        atomicAdd(&rowsum[brow + wm * 128 + mi * 32 + (g & 3) + 8 * (g >> 2) + 4 * hi], s);
    }
  // Col sums: lane-local over mi,g; combine the two hi halves.
  #pragma unroll
  for (int ni = 0; ni < 2; ++ni) {
    float cs = 0.f;
    #pragma unroll
    for (int mi = 0; mi < 4; ++mi)
      #pragma unroll
      for (int g = 0; g < 16; ++g) cs += acc[mi][ni][g];
    cs += __shfl_xor(cs, 32);
    if (hi == 0)
      atomicAdd(&rowsum[bcol + wn * 64 + ni * 32 + l31], cs);
  }
}

// ---------------------------------------------------------------------------
// Kernel B2: diagonal band, fp8. 64 cells of 128x256; gcol > grow keeps each
// within-cell strict pair once. Per wave: 64x64 = 2x2 frags of 32x32.
// Buffer: A[128][64]@0 (8 KB) + B[256][64]@8192 (16 KB) = 24 KB x 3 bufs.
// ---------------------------------------------------------------------------
__global__ __launch_bounds__(512) void ntxent_gemm_diag(
    const unsigned char* __restrict__ Z, float* __restrict__ rowsum) {
  __shared__ unsigned char lds[3 * 24576];

  const int t    = threadIdx.x;
  const int wid  = t >> 6;
  const int lane = t & 63;
  const int l31  = lane & 31;
  const int hi   = lane >> 5;
  const int wm   = wid >> 2;        // 0..1: 64-row half of 128 rows
  const int wn   = wid & 3;         // 0..3: 64-col quarter of 256 cols

  const int d = blockIdx.x >> 1;
  const int arow0 = d * 256 + (blockIdx.x & 1) * 128;
  const int bcol0 = d * 256;

  auto stageA = [&](int kt, int buf) {      // 512 chunks = 1 gload/wave
    const int cb = wid * 64;
    const int c  = cb + lane;
    const int r  = c >> 2;
    const int lc = (c & 3) ^ (r & 3) ^ ((r >> 2) & 3);
    GLOAD_LDS16(Z + (size_t)(arow0 + r) * DIM + kt * 64 + lc * 16,
                lds + buf * 24576 + cb * 16);
  };
  auto stageB = [&](int kt, int buf, int half) {   // 2 gloads/wave
    const int cb = half * 512 + wid * 64;
    const int c  = cb + lane;
    const int r  = c >> 2;
    const int lc = (c & 3) ^ (r & 3) ^ ((r >> 2) & 3);
    GLOAD_LDS16(Z + (size_t)(bcol0 + r) * DIM + kt * 64 + lc * 16,
                lds + buf * 24576 + 8192 + cb * 16);
  };
  auto frag = [&](int buf, int opoff, int row) -> i32x8 {
    const unsigned char* base = lds + buf * 24576 + opoff + row * 64;
    const int swz = (row & 3) ^ ((row >> 2) & 3);
    const i32x4 lo = *(const i32x4*)(base + (((2 * hi)     ^ swz) << 4));
    const i32x4 hp = *(const i32x4*)(base + (((2 * hi + 1) ^ swz) << 4));
    i32x8 r8;
    r8[0] = lo[0]; r8[1] = lo[1]; r8[2] = lo[2]; r8[3] = lo[3];
    r8[4] = hp[0]; r8[5] = hp[1]; r8[6] = hp[2]; r8[7] = hp[3];
    return r8;
  };

  f32x16 acc[2][2];
  #pragma unroll
  for (int mi = 0; mi < 2; ++mi)
    #pragma unroll
    for (int ni = 0; ni < 2; ++ni)
      #pragma unroll
      for (int g = 0; g < 16; ++g) acc[mi][ni][g] = 0.f;

  stageA(0, 0); stageB(0, 0, 0); stageB(0, 0, 1);
  stageA(1, 1); stageB(1, 1, 0); stageB(1, 1, 1);
  asm volatile("s_waitcnt vmcnt(3)" ::: "memory");
  __builtin_amdgcn_s_barrier();

  int bcur = 0, bnext = 1, bfree = 2;
  for (int kt = 0; kt < NKT; ++kt) {
    i32x8 A0 = frag(bcur, 0, wm * 64 + 0  + l31);
    i32x8 A1 = frag(bcur, 0, wm * 64 + 32 + l31);
    i32x8 B0 = frag(bcur, 8192, wn * 64 + 0  + l31);
    i32x8 B1 = frag(bcur, 8192, wn * 64 + 32 + l31);
    if (kt + 2 < NKT) {
      stageA(kt + 2, bfree);
      stageB(kt + 2, bfree, 0);
      stageB(kt + 2, bfree, 1);
    }
    asm volatile("s_waitcnt lgkmcnt(0)" ::: "memory");
    __builtin_amdgcn_sched_barrier(0);
    __builtin_amdgcn_s_setprio(1);
    acc[0][0] = MFMA_FP8(A0, B0, acc[0][0]);
    acc[0][1] = MFMA_FP8(A0, B1, acc[0][1]);
    acc[1][0] = MFMA_FP8(A1, B0, acc[1][0]);
    acc[1][1] = MFMA_FP8(A1, B1, acc[1][1]);
    __builtin_amdgcn_s_setprio(0);
    if (kt + 2 < NKT) {
      asm volatile("s_waitcnt vmcnt(3)" ::: "memory");
    } else if (kt + 1 < NKT) {
      asm volatile("s_waitcnt vmcnt(0)" ::: "memory");
    }
    __builtin_amdgcn_s_barrier();
    const int tmp = bcur; bcur = bnext; bnext = bfree; bfree = tmp;
  }

  // Keep only gcol > grow (each within-cell pair once; diagonal excluded).
  #pragma unroll
  for (int mi = 0; mi < 2; ++mi)
    #pragma unroll
    for (int ni = 0; ni < 2; ++ni) {
      const int gcol = bcol0 + wn * 64 + ni * 32 + l31;
      #pragma unroll
      for (int g = 0; g < 16; ++g) {
        const int grow = arow0 + wm * 64 + mi * 32 + (g & 3) + 8 * (g >> 2) + 4 * hi;
        const float v = acc[mi][ni][g];
        acc[mi][ni][g] = (gcol > grow) ? __expf((v - 1.0f) * INV_T) : 0.f;
      }
    }
  #pragma unroll
  for (int mi = 0; mi < 2; ++mi)
    #pragma unroll
    for (int g = 0; g < 16; ++g) {
      float s = acc[mi][0][g] + acc[mi][1][g];
      s += __shfl_xor(s, 1);
      s += __shfl_xor(s, 2);
      s += __shfl_xor(s, 4);
      s += __shfl_xor(s, 8);
      s += __shfl_xor(s, 16);
      if (l31 == 0)
        atomicAdd(&rowsum[arow0 + wm * 64 + mi * 32 + (g & 3) + 8 * (g >> 2) + 4 * hi], s);
    }
  #pragma unroll
  for (int ni = 0; ni < 2; ++ni) {
    float cs = 0.f;
    #pragma unroll
    for (int mi = 0; mi < 2; ++mi)
      #pragma unroll
      for (int g = 0; g < 16; ++g) cs += acc[mi][ni][g];
    cs += __shfl_xor(cs, 32);
    if (hi == 0)
      atomicAdd(&rowsum[bcol0 + wn * 64 + ni * 32 + l31], cs);
  }
}

// ---------------------------------------------------------------------------
// Kernel C: loss = 1/T + mean(log rowsum) - mean(pos)
// ---------------------------------------------------------------------------
__global__ __launch_bounds__(1024) void finalize_kernel(
    const float* __restrict__ rowsum, const float* __restrict__ pos,
    float* __restrict__ out) {
  const int t = threadIdx.x;
  float ls = 0.f, ps = 0.f;
  for (int i = t; i < NROWS; i += 1024) ls += logf(rowsum[i]);
  for (int i = t; i < NPAIR; i += 1024) ps += pos[i];
  #pragma unroll
  for (int off = 32; off; off >>= 1) {
    ls += __shfl_down(ls, off);
    ps += __shfl_down(ps, off);
  }
  __shared__ float sls[16], sps[16];
  const int wave = t >> 6, lane = t & 63;
  if (lane == 0) { sls[wave] = ls; sps[wave] = ps; }
  __syncthreads();
  if (t == 0) {
    float LS = 0.f, PS = 0.f;
    #pragma unroll
    for (int w = 0; w < 16; ++w) { LS += sls[w]; PS += sps[w]; }
    out[0] = INV_T + LS / (float)NROWS - PS / (float)NPAIR;
  }
}

extern "C" void kernel_launch(void* const* d_in, const int* in_sizes, int n_in,
                              void* d_out, int out_size, void* d_ws, size_t ws_size,
                              hipStream_t stream) {
  const float* l1 = (const float*)d_in[0];
  const float* l2 = (const float*)d_in[1];
  float* out = (float*)d_out;

  char* ws = (char*)d_ws;
  unsigned char* Z = (unsigned char*)ws;                   // 8 MB fp8
  float* rowsum = (float*)(ws + (size_t)NROWS * DIM);      // 32 KB
  float* pos    = rowsum + NROWS;                          // 16 KB

  normalize_kernel<<<NPAIR, 256, 0, stream>>>(l1, l2, Z, pos, rowsum);
  ntxent_gemm_offdiag<<<NOFF, 512, 0, stream>>>(Z, rowsum);
  ntxent_gemm_diag<<<64, 512, 0, stream>>>(Z, rowsum);
  finalize_kernel<<<1, 1024, 0, stream>>>(rowsum, pos, out);
}

// Round 7
// 354.162 us; speedup vs baseline: 1.0089x; 1.0089x over previous
//
#include <hip/hip_runtime.h>
#include <hip/hip_bf16.h>

// NT-Xent loss. N=4096 pairs, D=1024, 2N=8192 rows.
// loss = 1/T + mean_i log( sum_{j != i} exp(sim_ij - 1/T) ) - mean_i pos_i
// sim = Z Z^T (cosine); fixed max 1/T (cosine bound) -> no online max.
// R2: triangular symmetry (each pair feeds row+col sums).
// R5: 496 off-diag 256^2 cells = 2 clean dispatch rounds; diag band peeled.
// R6: fp8 e4m3 + mfma_scale_f32_32x32x64_f8f6f4 (unit scales) -- layout
//     verified correct (absmax 0) but spilled: acc f32x16 x8 stays in arch
//     VGPRs, default cap 128 -> ~485 MB scratch writes, 3x regression.
// R7: __launch_bounds__(512, 2) -> 256-reg budget, demand ~210 fits.

#define NPAIR 4096
#define NROWS 8192
#define DIM   1024
#define NOFF  496                   // strict off-diag 256^2 cells (32*31/2)
#define NKT   16                    // K-tiles of 64
#define INV_T 14.285714285714286f   // 1/0.07
#define SCL1  0x7F                  // E8M0 exponent 127 -> scale 2^0 = 1.0

typedef __attribute__((ext_vector_type(4)))  int   i32x4;
typedef __attribute__((ext_vector_type(8)))  int   i32x8;
typedef __attribute__((ext_vector_type(16))) float f32x16;

#define GLOAD_LDS16(g, l)                                              \
  __builtin_amdgcn_global_load_lds(                                    \
      (const __attribute__((address_space(1))) void*)(g),              \
      (__attribute__((address_space(3))) void*)(l), 16, 0, 0)

#define MFMA_FP8(A, B, C)                                              \
  __builtin_amdgcn_mfma_scale_f32_32x32x64_f8f6f4(                     \
      (A), (B), (C), 0, 0, 0, SCL1, 0, SCL1)

// ---------------------------------------------------------------------------
// Kernel A: per pair-row i: norms + cross dot (fp32); write fp8 e4m3
// normalized rows Z[i], Z[i+NPAIR]; pos[i] = cos/T; zero rowsum (2/block).
// ---------------------------------------------------------------------------
__global__ __launch_bounds__(256) void normalize_kernel(
    const float* __restrict__ l1, const float* __restrict__ l2,
    unsigned char* __restrict__ Z, float* __restrict__ pos,
    float* __restrict__ rowsum) {
  const int i = blockIdx.x;
  const int t = threadIdx.x;           // one float4 per thread
  if (t < 2) rowsum[i * 2 + t] = 0.f;
  const float4 a = ((const float4*)(l1 + (size_t)i * DIM))[t];
  const float4 b = ((const float4*)(l2 + (size_t)i * DIM))[t];
  float s1 = a.x*a.x + a.y*a.y + a.z*a.z + a.w*a.w;
  float s2 = b.x*b.x + b.y*b.y + b.z*b.z + b.w*b.w;
  float d  = a.x*b.x + a.y*b.y + a.z*b.z + a.w*b.w;

  #pragma unroll
  for (int off = 32; off; off >>= 1) {
    s1 += __shfl_down(s1, off);
    s2 += __shfl_down(s2, off);
    d  += __shfl_down(d,  off);
  }
  __shared__ float red[3][4];
  __shared__ float fin[3];
  const int wave = t >> 6, lane = t & 63;
  if (lane == 0) { red[0][wave] = s1; red[1][wave] = s2; red[2][wave] = d; }
  __syncthreads();
  if (t == 0) {
    float S1 = red[0][0] + red[0][1] + red[0][2] + red[0][3];
    float S2 = red[1][0] + red[1][1] + red[1][2] + red[1][3];
    float DD = red[2][0] + red[2][1] + red[2][2] + red[2][3];
    float r1 = rsqrtf(S1), r2 = rsqrtf(S2);
    fin[0] = r1; fin[1] = r2;
    pos[i] = DD * r1 * r2 * INV_T;
  }
  __syncthreads();
  const float r1 = fin[0], r2 = fin[1];
  int pa = __builtin_amdgcn_cvt_pk_fp8_f32(a.x * r1, a.y * r1, 0, false);
  pa     = __builtin_amdgcn_cvt_pk_fp8_f32(a.z * r1, a.w * r1, pa, true);
  int pb = __builtin_amdgcn_cvt_pk_fp8_f32(b.x * r2, b.y * r2, 0, false);
  pb     = __builtin_amdgcn_cvt_pk_fp8_f32(b.z * r2, b.w * r2, pb, true);
  ((int*)(Z + (size_t)i * DIM))[t] = pa;
  ((int*)(Z + (size_t)(i + NPAIR) * DIM))[t] = pb;
}

// ---------------------------------------------------------------------------
// Kernel B1: 496 strict off-diagonal 256x256 cells, fp8 MX GEMM.
// Per wave (8 waves, 2Mx4N): output 128x64 = 4 M-frags x 2 N-frags of 32x32.
// BK=64, 3-buffer LDS (96 KB), 2-deep prefetch, counted vmcnt(4),
// 1 barrier per K-tile. Frag: row/col = lane&31, k = (lane>>5)*32 + [0..31].
// LDS 16B-chunk XOR swizzle: phys = logical ^ (r&3) ^ ((r>>2)&3).
// ---------------------------------------------------------------------------
__global__ __launch_bounds__(512, 2) void ntxent_gemm_offdiag(
    const unsigned char* __restrict__ Z, float* __restrict__ rowsum) {
  __shared__ unsigned char lds[3 * 32768];   // buf: A[256][64]@0, B[256][64]@16384

  const int t    = threadIdx.x;
  const int wid  = t >> 6;
  const int lane = t & 63;
  const int l31  = lane & 31;
  const int hi   = lane >> 5;
  const int wm   = wid >> 2;        // 0..1: 128-row half
  const int wn   = wid & 3;         // 0..3: 64-col quarter

  // T1: bijective XCD swizzle (496 = 8*62) + strict-upper decode (bi < bj).
  const int idx = (blockIdx.x & 7) * 62 + (blockIdx.x >> 3);
  int bj = (int)((1.0f + sqrtf(1.0f + 8.0f * (float)idx)) * 0.5f);
  while (bj * (bj - 1) / 2 > idx) --bj;
  while ((bj + 1) * bj / 2 <= idx) ++bj;
  const int bi = idx - bj * (bj - 1) / 2;
  const int brow = bi * 256, bcol = bj * 256;

  // Stage one 256x64 fp8 op-tile (16 KB = 1024 16B-chunks; 2 gloads/wave).
  auto stage = [&](int kt, int buf, int rowbase, int opoff) {
    #pragma unroll
    for (int i = 0; i < 2; ++i) {
      const int cb = wid * 128 + i * 64;     // wave-uniform chunk base
      const int c  = cb + lane;
      const int r  = c >> 2;
      const int lc = (c & 3) ^ (r & 3) ^ ((r >> 2) & 3);
      GLOAD_LDS16(Z + (size_t)(rowbase + r) * DIM + kt * 64 + lc * 16,
                  lds + buf * 32768 + opoff + cb * 16);
    }
  };
  // Read one lane's 32-byte fragment (row = frag row, k = hi*32 + [0..31]).
  auto frag = [&](int buf, int opoff, int row) -> i32x8 {
    const unsigned char* base = lds + buf * 32768 + opoff + row * 64;
    const int swz = (row & 3) ^ ((row >> 2) & 3);
    const i32x4 lo = *(const i32x4*)(base + (((2 * hi)     ^ swz) << 4));
    const i32x4 hp = *(const i32x4*)(base + (((2 * hi + 1) ^ swz) << 4));
    i32x8 r8;
    r8[0] = lo[0]; r8[1] = lo[1]; r8[2] = lo[2]; r8[3] = lo[3];
    r8[4] = hp[0]; r8[5] = hp[1]; r8[6] = hp[2]; r8[7] = hp[3];
    return r8;
  };

  f32x16 acc[4][2];
  #pragma unroll
  for (int mi = 0; mi < 4; ++mi)
    #pragma unroll
    for (int ni = 0; ni < 2; ++ni)
      #pragma unroll
      for (int g = 0; g < 16; ++g) acc[mi][ni][g] = 0.f;

  // Prologue: stage tiles 0,1; drain tile 0 (vmcnt 4 = allow tile1's 4).
  stage(0, 0, brow, 0); stage(0, 0, bcol, 16384);
  stage(1, 1, brow, 0); stage(1, 1, bcol, 16384);
  asm volatile("s_waitcnt vmcnt(4)" ::: "memory");
  __builtin_amdgcn_s_barrier();

  int bcur = 0, bnext = 1, bfree = 2;
  for (int kt = 0; kt < NKT; ++kt) {
    i32x8 A0 = frag(bcur, 0, wm * 128 + 0  + l31);
    i32x8 A1 = frag(bcur, 0, wm * 128 + 32 + l31);
    i32x8 A2 = frag(bcur, 0, wm * 128 + 64 + l31);
    i32x8 A3 = frag(bcur, 0, wm * 128 + 96 + l31);
    i32x8 B0 = frag(bcur, 16384, wn * 64 + 0  + l31);
    i32x8 B1 = frag(bcur, 16384, wn * 64 + 32 + l31);
    if (kt + 2 < NKT) {                      // prefetch 2 ahead
      stage(kt + 2, bfree, brow, 0);
      stage(kt + 2, bfree, bcol, 16384);
    }
    asm volatile("s_waitcnt lgkmcnt(0)" ::: "memory");
    __builtin_amdgcn_sched_barrier(0);
    __builtin_amdgcn_s_setprio(1);
    acc[0][0] = MFMA_FP8(A0, B0, acc[0][0]);
    acc[0][1] = MFMA_FP8(A0, B1, acc[0][1]);
    acc[1][0] = MFMA_FP8(A1, B0, acc[1][0]);
    acc[1][1] = MFMA_FP8(A1, B1, acc[1][1]);
    acc[2][0] = MFMA_FP8(A2, B0, acc[2][0]);
    acc[2][1] = MFMA_FP8(A2, B1, acc[2][1]);
    acc[3][0] = MFMA_FP8(A3, B0, acc[3][0]);
    acc[3][1] = MFMA_FP8(A3, B1, acc[3][1]);
    __builtin_amdgcn_s_setprio(0);
    if (kt + 2 < NKT) {
      asm volatile("s_waitcnt vmcnt(4)" ::: "memory");   // tile kt+1 ready
    } else if (kt + 1 < NKT) {
      asm volatile("s_waitcnt vmcnt(0)" ::: "memory");   // last tile
    }
    __builtin_amdgcn_s_barrier();
    const int tmp = bcur; bcur = bnext; bnext = bfree; bfree = tmp;
  }

  // Epilogue. 32x32 C/D layout: col = lane&31, row = (g&3)+8*(g>>2)+4*hi.
  // Strict off-diag cell: every element is a valid pair, no mask.
  #pragma unroll
  for (int mi = 0; mi < 4; ++mi)
    #pragma unroll
    for (int ni = 0; ni < 2; ++ni)
      #pragma unroll
      for (int g = 0; g < 16; ++g)
        acc[mi][ni][g] = __expf((acc[mi][ni][g] - 1.0f) * INV_T);
  // Row sums: reduce across the 32 cols (lanes within each hi half).
  #pragma unroll
  for (int mi = 0; mi < 4; ++mi)
    #pragma unroll
    for (int g = 0; g < 16; ++g) {
      float s = acc[mi][0][g] + acc[mi][1][g];
      s += __shfl_xor(s, 1);
      s += __shfl_xor(s, 2);
      s += __shfl_xor(s, 4);
      s += __shfl_xor(s, 8);
      s += __shfl_xor(s, 16);
      if (l31 == 0)
        atomicAdd(&rowsum[brow + wm * 128 + mi * 32 + (g & 3) + 8 * (g >> 2) + 4 * hi], s);
    }
  // Col sums: lane-local over mi,g; combine the two hi halves.
  #pragma unroll
  for (int ni = 0; ni < 2; ++ni) {
    float cs = 0.f;
    #pragma unroll
    for (int mi = 0; mi < 4; ++mi)
      #pragma unroll
      for (int g = 0; g < 16; ++g) cs += acc[mi][ni][g];
    cs += __shfl_xor(cs, 32);
    if (hi == 0)
      atomicAdd(&rowsum[bcol + wn * 64 + ni * 32 + l31], cs);
  }
}

// ---------------------------------------------------------------------------
// Kernel B2: diagonal band, fp8. 64 cells of 128x256; gcol > grow keeps each
// within-cell strict pair once. Per wave: 64x64 = 2x2 frags of 32x32.
// Buffer: A[128][64]@0 (8 KB) + B[256][64]@8192 (16 KB) = 24 KB x 3 bufs.
// ---------------------------------------------------------------------------
__global__ __launch_bounds__(512, 2) void ntxent_gemm_diag(
    const unsigned char* __restrict__ Z, float* __restrict__ rowsum) {
  __shared__ unsigned char lds[3 * 24576];

  const int t    = threadIdx.x;
  const int wid  = t >> 6;
  const int lane = t & 63;
  const int l31  = lane & 31;
  const int hi   = lane >> 5;
  const int wm   = wid >> 2;        // 0..1: 64-row half of 128 rows
  const int wn   = wid & 3;         // 0..3: 64-col quarter of 256 cols

  const int d = blockIdx.x >> 1;
  const int arow0 = d * 256 + (blockIdx.x & 1) * 128;
  const int bcol0 = d * 256;

  auto stageA = [&](int kt, int buf) {      // 512 chunks = 1 gload/wave
    const int cb = wid * 64;
    const int c  = cb + lane;
    const int r  = c >> 2;
    const int lc = (c & 3) ^ (r & 3) ^ ((r >> 2) & 3);
    GLOAD_LDS16(Z + (size_t)(arow0 + r) * DIM + kt * 64 + lc * 16,
                lds + buf * 24576 + cb * 16);
  };
  auto stageB = [&](int kt, int buf, int half) {   // 2 gloads/wave
    const int cb = half * 512 + wid * 64;
    const int c  = cb + lane;
    const int r  = c >> 2;
    const int lc = (c & 3) ^ (r & 3) ^ ((r >> 2) & 3);
    GLOAD_LDS16(Z + (size_t)(bcol0 + r) * DIM + kt * 64 + lc * 16,
                lds + buf * 24576 + 8192 + cb * 16);
  };
  auto frag = [&](int buf, int opoff, int row) -> i32x8 {
    const unsigned char* base = lds + buf * 24576 + opoff + row * 64;
    const int swz = (row & 3) ^ ((row >> 2) & 3);
    const i32x4 lo = *(const i32x4*)(base + (((2 * hi)     ^ swz) << 4));
    const i32x4 hp = *(const i32x4*)(base + (((2 * hi + 1) ^ swz) << 4));
    i32x8 r8;
    r8[0] = lo[0]; r8[1] = lo[1]; r8[2] = lo[2]; r8[3] = lo[3];
    r8[4] = hp[0]; r8[5] = hp[1]; r8[6] = hp[2]; r8[7] = hp[3];
    return r8;
  };

  f32x16 acc[2][2];
  #pragma unroll
  for (int mi = 0; mi < 2; ++mi)
    #pragma unroll
    for (int ni = 0; ni < 2; ++ni)
      #pragma unroll
      for (int g = 0; g < 16; ++g) acc[mi][ni][g] = 0.f;

  stageA(0, 0); stageB(0, 0, 0); stageB(0, 0, 1);
  stageA(1, 1); stageB(1, 1, 0); stageB(1, 1, 1);
  asm volatile("s_waitcnt vmcnt(3)" ::: "memory");
  __builtin_amdgcn_s_barrier();

  int bcur = 0, bnext = 1, bfree = 2;
  for (int kt = 0; kt < NKT; ++kt) {
    i32x8 A0 = frag(bcur, 0, wm * 64 + 0  + l31);
    i32x8 A1 = frag(bcur, 0, wm * 64 + 32 + l31);
    i32x8 B0 = frag(bcur, 8192, wn * 64 + 0  + l31);
    i32x8 B1 = frag(bcur, 8192, wn * 64 + 32 + l31);
    if (kt + 2 < NKT) {
      stageA(kt + 2, bfree);
      stageB(kt + 2, bfree, 0);
      stageB(kt + 2, bfree, 1);
    }
    asm volatile("s_waitcnt lgkmcnt(0)" ::: "memory");
    __builtin_amdgcn_sched_barrier(0);
    __builtin_amdgcn_s_setprio(1);
    acc[0][0] = MFMA_FP8(A0, B0, acc[0][0]);
    acc[0][1] = MFMA_FP8(A0, B1, acc[0][1]);
    acc[1][0] = MFMA_FP8(A1, B0, acc[1][0]);
    acc[1][1] = MFMA_FP8(A1, B1, acc[1][1]);
    __builtin_amdgcn_s_setprio(0);
    if (kt + 2 < NKT) {
      asm volatile("s_waitcnt vmcnt(3)" ::: "memory");
    } else if (kt + 1 < NKT) {
      asm volatile("s_waitcnt vmcnt(0)" ::: "memory");
    }
    __builtin_amdgcn_s_barrier();
    const int tmp = bcur; bcur = bnext; bnext = bfree; bfree = tmp;
  }

  // Keep only gcol > grow (each within-cell pair once; diagonal excluded).
  #pragma unroll
  for (int mi = 0; mi < 2; ++mi)
    #pragma unroll
    for (int ni = 0; ni < 2; ++ni) {
      const int gcol = bcol0 + wn * 64 + ni * 32 + l31;
      #pragma unroll
      for (int g = 0; g < 16; ++g) {
        const int grow = arow0 + wm * 64 + mi * 32 + (g & 3) + 8 * (g >> 2) + 4 * hi;
        const float v = acc[mi][ni][g];
        acc[mi][ni][g] = (gcol > grow) ? __expf((v - 1.0f) * INV_T) : 0.f;
      }
    }
  #pragma unroll
  for (int mi = 0; mi < 2; ++mi)
    #pragma unroll
    for (int g = 0; g < 16; ++g) {
      float s = acc[mi][0][g] + acc[mi][1][g];
      s += __shfl_xor(s, 1);
      s += __shfl_xor(s, 2);
      s += __shfl_xor(s, 4);
      s += __shfl_xor(s, 8);
      s += __shfl_xor(s, 16);
      if (l31 == 0)
        atomicAdd(&rowsum[arow0 + wm * 64 + mi * 32 + (g & 3) + 8 * (g >> 2) + 4 * hi], s);
    }
  #pragma unroll
  for (int ni = 0; ni < 2; ++ni) {
    float cs = 0.f;
    #pragma unroll
    for (int mi = 0; mi < 2; ++mi)
      #pragma unroll
      for (int g = 0; g < 16; ++g) cs += acc[mi][ni][g];
    cs += __shfl_xor(cs, 32);
    if (hi == 0)
      atomicAdd(&rowsum[bcol0 + wn * 64 + ni * 32 + l31], cs);
  }
}

// ---------------------------------------------------------------------------
// Kernel C: loss = 1/T + mean(log rowsum) - mean(pos)
// ---------------------------------------------------------------------------
__global__ __launch_bounds__(1024) void finalize_kernel(
    const float* __restrict__ rowsum, const float* __restrict__ pos,
    float* __restrict__ out) {
  const int t = threadIdx.x;
  float ls = 0.f, ps = 0.f;
  for (int i = t; i < NROWS; i += 1024) ls += logf(rowsum[i]);
  for (int i = t; i < NPAIR; i += 1024) ps += pos[i];
  #pragma unroll
  for (int off = 32; off; off >>= 1) {
    ls += __shfl_down(ls, off);
    ps += __shfl_down(ps, off);
  }
  __shared__ float sls[16], sps[16];
  const int wave = t >> 6, lane = t & 63;
  if (lane == 0) { sls[wave] = ls; sps[wave] = ps; }
  __syncthreads();
  if (t == 0) {
    float LS = 0.f, PS = 0.f;
    #pragma unroll
    for (int w = 0; w < 16; ++w) { LS += sls[w]; PS += sps[w]; }
    out[0] = INV_T + LS / (float)NROWS - PS / (float)NPAIR;
  }
}

extern "C" void kernel_launch(void* const* d_in, const int* in_sizes, int n_in,
                              void* d_out, int out_size, void* d_ws, size_t ws_size,
                              hipStream_t stream) {
  const float* l1 = (const float*)d_in[0];
  const float* l2 = (const float*)d_in[1];
  float* out = (float*)d_out;

  char* ws = (char*)d_ws;
  unsigned char* Z = (unsigned char*)ws;                   // 8 MB fp8
  float* rowsum = (float*)(ws + (size_t)NROWS * DIM);      // 32 KB
  float* pos    = rowsum + NROWS;                          // 16 KB

  normalize_kernel<<<NPAIR, 256, 0, stream>>>(l1, l2, Z, pos, rowsum);
  ntxent_gemm_offdiag<<<NOFF, 512, 0, stream>>>(Z, rowsum);
  ntxent_gemm_diag<<<64, 512, 0, stream>>>(Z, rowsum);
  finalize_kernel<<<1, 1024, 0, stream>>>(rowsum, pos, out);
}